// Round 1
// baseline (710.445 us; speedup 1.0000x reference)
//
#include <hip/hip_runtime.h>
#include <math.h>

#define NN 50000
#define NE 800000
#define KDIM 128

// ---------------- GEMM: Y[nrows x OUT] = X[nrows x 128] @ W[128 x OUT] ----------------
// fp32, LDS-tiled. BM=64, BN=128, KC=32, 256 threads, 4x8 micro-tile per thread.
constexpr int BM = 64, BN = 128, KC = 32;

__global__ __launch_bounds__(256) void gemm_kernel(
    const float* __restrict__ X, const float* __restrict__ W,
    float* __restrict__ Y, int nrows, int OUT) {
  __shared__ __align__(16) float XsT[KC][BM + 4];   // k-major, padded (+4 keeps float4 alignment, breaks bank strides)
  __shared__ __align__(16) float Ws[KC][BN + 4];
  const int tid = threadIdx.x;
  const int row0 = blockIdx.x * BM;
  const int c  = tid & 15;   // col group: cols 4c..4c+3 and 64+4c..64+4c+3
  const int rg = tid >> 4;   // row group: rows 4rg..4rg+3

  float acc[4][8];
#pragma unroll
  for (int i = 0; i < 4; i++)
#pragma unroll
    for (int j = 0; j < 8; j++) acc[i][j] = 0.f;

  const int lr  = tid >> 2;  // X-load row 0..63
  const int lq  = tid & 3;   // X-load slot base
  const int wk  = tid >> 3;  // W-load k 0..31
  const int ws0 = tid & 7;   // W-load slot base

  for (int k0 = 0; k0 < KDIM; k0 += KC) {
    // stage X tile transposed: XsT[k][row]
#pragma unroll
    for (int i = 0; i < 2; i++) {
      int slot = lq + i * 4;      // 0..7
      int kk = slot * 4;
      float4 v = make_float4(0.f, 0.f, 0.f, 0.f);
      int grow = row0 + lr;
      if (grow < nrows) v = *(const float4*)&X[(size_t)grow * KDIM + k0 + kk];
      XsT[kk + 0][lr] = v.x; XsT[kk + 1][lr] = v.y;
      XsT[kk + 2][lr] = v.z; XsT[kk + 3][lr] = v.w;
    }
    // stage W tile: Ws[k][col]
#pragma unroll
    for (int i = 0; i < 4; i++) {
      int slot = ws0 + i * 8;     // 0..31
      int col4 = slot * 4;
      float4 v = make_float4(0.f, 0.f, 0.f, 0.f);
      if (col4 < OUT) v = *(const float4*)&W[(size_t)(k0 + wk) * OUT + col4];
      *(float4*)&Ws[wk][col4] = v;
    }
    __syncthreads();
#pragma unroll
    for (int k = 0; k < KC; ++k) {
      float4 a  = *(const float4*)&XsT[k][rg * 4];
      float4 p0 = *(const float4*)&Ws[k][c * 4];
      float4 p1 = *(const float4*)&Ws[k][c * 4 + 64];
      float av[4] = {a.x, a.y, a.z, a.w};
      float bv[8] = {p0.x, p0.y, p0.z, p0.w, p1.x, p1.y, p1.z, p1.w};
#pragma unroll
      for (int i = 0; i < 4; i++)
#pragma unroll
        for (int j = 0; j < 8; j++) acc[i][j] = fmaf(av[i], bv[j], acc[i][j]);
    }
    __syncthreads();
  }
#pragma unroll
  for (int i = 0; i < 4; i++) {
    int grow = row0 + rg * 4 + i;
    if (grow >= nrows) continue;
#pragma unroll
    for (int j = 0; j < 8; j++) {
      int col = (j < 4) ? (c * 4 + j) : (64 + c * 4 + (j - 4));
      if (col < OUT) Y[(size_t)grow * OUT + col] = acc[i][j];
    }
  }
}

// ---------------- per-node edge score: e = log(cos>=0.1 ? cos : 1e-6), cos = sq/max(sqrt(sq),1e-8)^2 ----------------
__global__ __launch_bounds__(256) void enode_kernel(
    const float* __restrict__ ft, float* __restrict__ e_node, int n, int F) {
  int gw = (blockIdx.x * blockDim.x + threadIdx.x) >> 6;
  int lane = threadIdx.x & 63;
  if (gw >= n) return;
  float sq = 0.f;
  for (int j = lane; j < F; j += 64) {
    float v = ft[(size_t)gw * F + j];
    sq = fmaf(v, v, sq);
  }
#pragma unroll
  for (int o = 32; o > 0; o >>= 1) sq += __shfl_xor(sq, o, 64);
  if (lane == 0) {
    float nrm = fmaxf(sqrtf(sq), 1e-8f);
    float cs = sq / (nrm * nrm);
    float cl = (cs >= 0.1f) ? cs : 1e-6f;
    e_node[gw] = logf(cl);
  }
}

// ---------------- segment softmax + weighted aggregation (+bias, +optional LN+ReLU), wave per dst node -----------
template <int F, bool LN>
__global__ __launch_bounds__(256) void agg_kernel(
    const float* __restrict__ ft, const float* __restrict__ e_node,
    const int* __restrict__ row_ptr, const int* __restrict__ es,
    const float* __restrict__ bias, const float* __restrict__ g,
    const float* __restrict__ beta, float* __restrict__ out, int n) {
  int gw = (blockIdx.x * blockDim.x + threadIdx.x) >> 6;
  int lane = threadIdx.x & 63;
  if (gw >= n) return;
  int b = row_ptr[gw], e = row_ptr[gw + 1];
  // segment max
  float m = -INFINITY;
  for (int i = b + lane; i < e; i += 64) m = fmaxf(m, e_node[es[i]]);
#pragma unroll
  for (int o = 32; o > 0; o >>= 1) m = fmaxf(m, __shfl_xor(m, o, 64));
  // segment sum of exp
  float s = 0.f;
  for (int i = b + lane; i < e; i += 64) s += expf(e_node[es[i]] - m);
#pragma unroll
  for (int o = 32; o > 0; o >>= 1) s += __shfl_xor(s, o, 64);
  float inv = 1.0f / fmaxf(s, 1e-16f);
  // weighted gather-sum
  float acc0 = 0.f, acc1 = 0.f;
  for (int i = b; i < e; ++i) {
    int sn = es[i];
    float a = expf(e_node[sn] - m) * inv;
    acc0 = fmaf(ft[(size_t)sn * F + lane], a, acc0);
    if (F == 128) acc1 = fmaf(ft[(size_t)sn * F + 64 + lane], a, acc1);
  }
  acc0 += bias[lane];
  if (F == 128) acc1 += bias[64 + lane];
  if (LN) {
    float sum = acc0 + acc1;
#pragma unroll
    for (int o = 32; o > 0; o >>= 1) sum += __shfl_xor(sum, o, 64);
    float mean = sum * (1.0f / 128.0f);
    float d0 = acc0 - mean, d1 = acc1 - mean;
    float v = d0 * d0 + d1 * d1;
#pragma unroll
    for (int o = 32; o > 0; o >>= 1) v += __shfl_xor(v, o, 64);
    float r = rsqrtf(v * (1.0f / 128.0f) + 1e-5f);
    float o0 = d0 * r * g[lane] + beta[lane];
    float o1 = d1 * r * g[64 + lane] + beta[64 + lane];
    out[(size_t)gw * 128 + lane] = fmaxf(o0, 0.f);
    out[(size_t)gw * 128 + 64 + lane] = fmaxf(o1, 0.f);
  } else {
    out[(size_t)gw * F + lane] = acc0;
  }
}

// ---------------- CSR build (by dst) ----------------
__global__ void count_kernel(const int* __restrict__ dst, int* __restrict__ counts, int E) {
  int e = blockIdx.x * blockDim.x + threadIdx.x;
  if (e < E) atomicAdd(&counts[dst[e]], 1);
}

__global__ __launch_bounds__(1024) void scan_kernel(
    const int* __restrict__ counts, int* __restrict__ row_ptr,
    int* __restrict__ fillp, int n) {
  __shared__ int sums[1024];
  int tid = threadIdx.x;
  int per = (n + 1023) >> 10;
  int start = tid * per;
  int local = 0;
  for (int i = 0; i < per; i++) {
    int idx = start + i;
    if (idx < n) local += counts[idx];
  }
  sums[tid] = local;
  __syncthreads();
  for (int off = 1; off < 1024; off <<= 1) {
    int t = (tid >= off) ? sums[tid - off] : 0;
    __syncthreads();
    sums[tid] += t;
    __syncthreads();
  }
  int run = sums[tid] - local;  // exclusive prefix over this thread's chunk
  for (int i = 0; i < per; i++) {
    int idx = start + i;
    if (idx < n) {
      int cv = counts[idx];
      row_ptr[idx] = run;
      fillp[idx] = run;
      run += cv;
    }
  }
  if (tid == 1023) row_ptr[n] = sums[1023];
}

__global__ void fill_kernel(const int* __restrict__ src, const int* __restrict__ dst,
                            int* __restrict__ fillp, int* __restrict__ es, int E) {
  int e = blockIdx.x * blockDim.x + threadIdx.x;
  if (e < E) {
    int d = dst[e];
    int pos = atomicAdd(&fillp[d], 1);
    es[pos] = src[e];
  }
}

// ---------------- orchestration ----------------
extern "C" void kernel_launch(void* const* d_in, const int* in_sizes, int n_in,
                              void* d_out, int out_size, void* d_ws, size_t ws_size,
                              hipStream_t stream) {
  (void)in_sizes; (void)n_in; (void)out_size; (void)ws_size;
  const float* feat = (const float*)d_in[0];
  const int* src = (const int*)d_in[1];
  const int* dst = (const int*)d_in[2];
  const float* W0 = (const float*)d_in[3];
  const float* b0 = (const float*)d_in[4];
  const float* W1 = (const float*)d_in[5];
  const float* b1 = (const float*)d_in[6];
  const float* W2 = (const float*)d_in[7];
  const float* b2 = (const float*)d_in[8];
  const float* ln1g = (const float*)d_in[9];
  const float* ln1b = (const float*)d_in[10];
  const float* ln2g = (const float*)d_in[11];
  const float* ln2b = (const float*)d_in[12];
  float* out = (float*)d_out;

  char* p = (char*)d_ws;
  auto alloc = [&](size_t bytes) {
    char* r = p;
    p += (bytes + 255) & ~size_t(255);
    return r;
  };
  float* ft     = (float*)alloc((size_t)NN * 128 * 4);
  float* h      = (float*)alloc((size_t)NN * 128 * 4);
  float* e_node = (float*)alloc((size_t)NN * 4);
  int* row_ptr  = (int*)alloc((size_t)(NN + 1) * 4);
  int* counts   = (int*)alloc((size_t)NN * 4);
  int* fillp    = (int*)alloc((size_t)NN * 4);
  int* es       = (int*)alloc((size_t)NE * 4);

  // CSR by dst (graph identical for all 3 convs)
  hipMemsetAsync(counts, 0, (size_t)NN * 4, stream);
  int eb = (NE + 255) / 256;
  count_kernel<<<eb, 256, 0, stream>>>(dst, counts, NE);
  scan_kernel<<<1, 1024, 0, stream>>>(counts, row_ptr, fillp, NN);
  fill_kernel<<<eb, 256, 0, stream>>>(src, dst, fillp, es, NE);

  int gb = (NN + BM - 1) / BM;
  int nwb = (NN + 3) / 4;  // 4 waves (256 threads) per block, wave per node

  // conv0: 128 -> 128, LN1 + ReLU
  gemm_kernel<<<gb, 256, 0, stream>>>(feat, W0, ft, NN, 128);
  enode_kernel<<<nwb, 256, 0, stream>>>(ft, e_node, NN, 128);
  agg_kernel<128, true><<<nwb, 256, 0, stream>>>(ft, e_node, row_ptr, es, b0, ln1g, ln1b, h, NN);
  // conv1: 128 -> 128, LN2 + ReLU
  gemm_kernel<<<gb, 256, 0, stream>>>(h, W1, ft, NN, 128);
  enode_kernel<<<nwb, 256, 0, stream>>>(ft, e_node, NN, 128);
  agg_kernel<128, true><<<nwb, 256, 0, stream>>>(ft, e_node, row_ptr, es, b1, ln2g, ln2b, h, NN);
  // conv2: 128 -> 64, no LN
  gemm_kernel<<<gb, 256, 0, stream>>>(h, W2, ft, NN, 64);
  enode_kernel<<<nwb, 256, 0, stream>>>(ft, e_node, NN, 64);
  agg_kernel<64, false><<<nwb, 256, 0, stream>>>(ft, e_node, row_ptr, es, b2, nullptr, nullptr, out, NN);
}

// Round 2
// 574.728 us; speedup vs baseline: 1.2361x; 1.2361x over previous
//
#include <hip/hip_runtime.h>
#include <math.h>

#define NN 50000
#define NE 800000
#define KDIM 128

// ---------------- GEMM: Y[nrows x OUT] = X[nrows x 128] @ W[128 x OUT] ----------------
// fp32, LDS-tiled. BM=64, BN=128, KC=32, 256 threads, 4x8 micro-tile per thread.
// Epilogue also computes e_node[row] = log(clamp(cos)) where cos = sq/max(sqrt(sq),eps)^2
// (fused: the block holds the full output row across 16 lanes).
constexpr int BM = 64, BN = 128, KC = 32;

__global__ __launch_bounds__(256) void gemm_kernel(
    const float* __restrict__ X, const float* __restrict__ W,
    float* __restrict__ Y, float* __restrict__ e_node, int nrows, int OUT) {
  __shared__ __align__(16) float XsT[KC][BM + 4];
  __shared__ __align__(16) float Ws[KC][BN + 4];
  const int tid = threadIdx.x;
  const int row0 = blockIdx.x * BM;
  const int c  = tid & 15;   // col group: cols 4c..4c+3 and 64+4c..64+4c+3
  const int rg = tid >> 4;   // row group: rows 4rg..4rg+3

  float acc[4][8];
#pragma unroll
  for (int i = 0; i < 4; i++)
#pragma unroll
    for (int j = 0; j < 8; j++) acc[i][j] = 0.f;

  const int lr  = tid >> 2;  // X-load row 0..63
  const int lq  = tid & 3;   // X-load slot base
  const int wk  = tid >> 3;  // W-load k 0..31
  const int ws0 = tid & 7;   // W-load slot base

  for (int k0 = 0; k0 < KDIM; k0 += KC) {
#pragma unroll
    for (int i = 0; i < 2; i++) {
      int slot = lq + i * 4;
      int kk = slot * 4;
      float4 v = make_float4(0.f, 0.f, 0.f, 0.f);
      int grow = row0 + lr;
      if (grow < nrows) v = *(const float4*)&X[(size_t)grow * KDIM + k0 + kk];
      XsT[kk + 0][lr] = v.x; XsT[kk + 1][lr] = v.y;
      XsT[kk + 2][lr] = v.z; XsT[kk + 3][lr] = v.w;
    }
#pragma unroll
    for (int i = 0; i < 4; i++) {
      int slot = ws0 + i * 8;
      int col4 = slot * 4;
      float4 v = make_float4(0.f, 0.f, 0.f, 0.f);
      if (col4 < OUT) v = *(const float4*)&W[(size_t)(k0 + wk) * OUT + col4];
      *(float4*)&Ws[wk][col4] = v;
    }
    __syncthreads();
#pragma unroll
    for (int k = 0; k < KC; ++k) {
      float4 a  = *(const float4*)&XsT[k][rg * 4];
      float4 p0 = *(const float4*)&Ws[k][c * 4];
      float4 p1 = *(const float4*)&Ws[k][c * 4 + 64];
      float av[4] = {a.x, a.y, a.z, a.w};
      float bv[8] = {p0.x, p0.y, p0.z, p0.w, p1.x, p1.y, p1.z, p1.w};
#pragma unroll
      for (int i = 0; i < 4; i++)
#pragma unroll
        for (int j = 0; j < 8; j++) acc[i][j] = fmaf(av[i], bv[j], acc[i][j]);
    }
    __syncthreads();
  }
#pragma unroll
  for (int i = 0; i < 4; i++) {
    int grow = row0 + rg * 4 + i;
    // fused e_node: sum of squares across the full row (cols >= OUT hold exact 0)
    float s = 0.f;
#pragma unroll
    for (int j = 0; j < 8; j++) s = fmaf(acc[i][j], acc[i][j], s);
#pragma unroll
    for (int o = 8; o > 0; o >>= 1) s += __shfl_xor(s, o, 64);  // reduce the 16 lanes sharing rg
    if (c == 0 && grow < nrows) {
      float nrm = fmaxf(sqrtf(s), 1e-8f);
      float cs = s / (nrm * nrm);
      e_node[grow] = logf(cs >= 0.1f ? cs : 1e-6f);
    }
    if (grow >= nrows) continue;
#pragma unroll
    for (int j = 0; j < 8; j++) {
      int col = (j < 4) ? (c * 4 + j) : (64 + c * 4 + (j - 4));
      if (col < OUT) Y[(size_t)grow * OUT + col] = acc[i][j];
    }
  }
}

// ---------------- segment softmax + weighted aggregation (+bias, +optional LN+ReLU), wave per dst node -----------
template <int F, bool LN>
__global__ __launch_bounds__(256) void agg_kernel(
    const float* __restrict__ ft, const float* __restrict__ e_node,
    const int* __restrict__ row_ptr, const int* __restrict__ es,
    const float* __restrict__ bias, const float* __restrict__ g,
    const float* __restrict__ beta, float* __restrict__ out, int n) {
  int gw = (blockIdx.x * blockDim.x + threadIdx.x) >> 6;
  int lane = threadIdx.x & 63;
  if (gw >= n) return;
  int b = row_ptr[gw], e = row_ptr[gw + 1];
  // segment max
  float m = -INFINITY;
  for (int i = b + lane; i < e; i += 64) m = fmaxf(m, e_node[es[i]]);
#pragma unroll
  for (int o = 32; o > 0; o >>= 1) m = fmaxf(m, __shfl_xor(m, o, 64));
  // segment sum of exp
  float s = 0.f;
  for (int i = b + lane; i < e; i += 64) s += expf(e_node[es[i]] - m);
#pragma unroll
  for (int o = 32; o > 0; o >>= 1) s += __shfl_xor(s, o, 64);
  float inv = 1.0f / fmaxf(s, 1e-16f);
  if (F == 128) {
    float2 acc = make_float2(0.f, 0.f);
    for (int i = b; i < e; ++i) {
      int sn = es[i];
      float a = expf(e_node[sn] - m) * inv;
      float2 v = *(const float2*)&ft[(size_t)sn * 128 + 2 * lane];
      acc.x = fmaf(v.x, a, acc.x);
      acc.y = fmaf(v.y, a, acc.y);
    }
    acc.x += bias[2 * lane];
    acc.y += bias[2 * lane + 1];
    if (LN) {
      float sum = acc.x + acc.y;
#pragma unroll
      for (int o = 32; o > 0; o >>= 1) sum += __shfl_xor(sum, o, 64);
      float mean = sum * (1.0f / 128.0f);
      float d0 = acc.x - mean, d1 = acc.y - mean;
      float v = d0 * d0 + d1 * d1;
#pragma unroll
      for (int o = 32; o > 0; o >>= 1) v += __shfl_xor(v, o, 64);
      float r = rsqrtf(v * (1.0f / 128.0f) + 1e-5f);
      float o0 = d0 * r * g[2 * lane] + beta[2 * lane];
      float o1 = d1 * r * g[2 * lane + 1] + beta[2 * lane + 1];
      float2 res = make_float2(fmaxf(o0, 0.f), fmaxf(o1, 0.f));
      *(float2*)&out[(size_t)gw * 128 + 2 * lane] = res;
    } else {
      *(float2*)&out[(size_t)gw * 128 + 2 * lane] = acc;
    }
  } else {
    float acc0 = 0.f;
    for (int i = b; i < e; ++i) {
      int sn = es[i];
      float a = expf(e_node[sn] - m) * inv;
      acc0 = fmaf(ft[(size_t)sn * F + lane], a, acc0);
    }
    acc0 += bias[lane];
    out[(size_t)gw * F + lane] = acc0;
  }
}

// ---------------- CSR build (by dst) ----------------
__global__ void count_kernel(const int* __restrict__ dst, int* __restrict__ counts, int E) {
  int e = blockIdx.x * blockDim.x + threadIdx.x;
  if (e < E) atomicAdd(&counts[dst[e]], 1);
}

// Stage A: per-block (1024 elements, 256 threads x int4) exclusive scan + block partial
__global__ __launch_bounds__(256) void scanA_kernel(
    const int* __restrict__ counts, int* __restrict__ lscan,
    int* __restrict__ partials, int n) {
  int tid = threadIdx.x;
  int base = blockIdx.x * 1024 + tid * 4;
  int4 v = make_int4(0, 0, 0, 0);
  if (base + 3 < n) v = *(const int4*)&counts[base];
  else {
    if (base + 0 < n) v.x = counts[base + 0];
    if (base + 1 < n) v.y = counts[base + 1];
    if (base + 2 < n) v.z = counts[base + 2];
  }
  int tsum = v.x + v.y + v.z + v.w;
  int lane = tid & 63, wid = tid >> 6;
  int x = tsum;
#pragma unroll
  for (int o = 1; o < 64; o <<= 1) {
    int y = __shfl_up(x, o, 64);
    if (lane >= o) x += y;
  }
  __shared__ int wsum[4];
  if (lane == 63) wsum[wid] = x;
  __syncthreads();
  int wpre = 0;
  for (int w = 0; w < wid; w++) wpre += wsum[w];
  int excl = wpre + x - tsum;
  int4 o4;
  o4.x = excl;
  o4.y = excl + v.x;
  o4.z = excl + v.x + v.y;
  o4.w = excl + v.x + v.y + v.z;
  if (base + 3 < n) *(int4*)&lscan[base] = o4;
  else {
    if (base + 0 < n) lscan[base + 0] = o4.x;
    if (base + 1 < n) lscan[base + 1] = o4.y;
    if (base + 2 < n) lscan[base + 2] = o4.z;
  }
  if (tid == 255) partials[blockIdx.x] = wpre + x;  // block total
}

// Stage C: add cross-block prefix (<=64 blocks), emit row_ptr and fillp
__global__ __launch_bounds__(256) void scanC_kernel(
    const int* __restrict__ lscan, const int* __restrict__ partials, int nblocks,
    int* __restrict__ row_ptr, int* __restrict__ fillp, int n) {
  __shared__ int s_prefix;
  int tid = threadIdx.x;
  if (tid < 64) {
    int pv = (tid < nblocks && tid < (int)blockIdx.x) ? partials[tid] : 0;
#pragma unroll
    for (int o = 32; o > 0; o >>= 1) pv += __shfl_xor(pv, o, 64);
    if (tid == 0) s_prefix = pv;
  }
  __syncthreads();
  int prefix = s_prefix;
  int base = blockIdx.x * 1024 + tid * 4;
#pragma unroll
  for (int q = 0; q < 4; q++) {
    int idx = base + q;
    if (idx < n) {
      int v = lscan[idx] + prefix;
      row_ptr[idx] = v;
      fillp[idx] = v;
    }
  }
  if (blockIdx.x == 0 && tid == 0) row_ptr[n] = NE;  // total edge count is static
}

__global__ void fill_kernel(const int* __restrict__ src, const int* __restrict__ dst,
                            int* __restrict__ fillp, int* __restrict__ es, int E) {
  int e = blockIdx.x * blockDim.x + threadIdx.x;
  if (e < E) {
    int d = dst[e];
    int pos = atomicAdd(&fillp[d], 1);
    es[pos] = src[e];
  }
}

// ---------------- orchestration ----------------
extern "C" void kernel_launch(void* const* d_in, const int* in_sizes, int n_in,
                              void* d_out, int out_size, void* d_ws, size_t ws_size,
                              hipStream_t stream) {
  (void)in_sizes; (void)n_in; (void)out_size; (void)ws_size;
  const float* feat = (const float*)d_in[0];
  const int* src = (const int*)d_in[1];
  const int* dst = (const int*)d_in[2];
  const float* W0 = (const float*)d_in[3];
  const float* b0 = (const float*)d_in[4];
  const float* W1 = (const float*)d_in[5];
  const float* b1 = (const float*)d_in[6];
  const float* W2 = (const float*)d_in[7];
  const float* b2 = (const float*)d_in[8];
  const float* ln1g = (const float*)d_in[9];
  const float* ln1b = (const float*)d_in[10];
  const float* ln2g = (const float*)d_in[11];
  const float* ln2b = (const float*)d_in[12];
  float* out = (float*)d_out;

  char* p = (char*)d_ws;
  auto alloc = [&](size_t bytes) {
    char* r = p;
    p += (bytes + 255) & ~size_t(255);
    return r;
  };
  float* ft      = (float*)alloc((size_t)NN * 128 * 4);
  float* h       = (float*)alloc((size_t)NN * 128 * 4);
  float* e_node  = (float*)alloc((size_t)NN * 4);
  int* row_ptr   = (int*)alloc((size_t)(NN + 1) * 4);
  int* counts    = (int*)alloc((size_t)NN * 4);
  int* fillp     = (int*)alloc((size_t)NN * 4);
  int* es        = (int*)alloc((size_t)NE * 4);
  int* lscan     = (int*)alloc((size_t)NN * 4);
  int* partials  = (int*)alloc(64 * 4);

  const int SCAN_BLOCKS = (NN + 1023) / 1024;  // 49 (<=64 required by scanC wave prefix)

  // CSR by dst (graph identical for all 3 convs)
  hipMemsetAsync(counts, 0, (size_t)NN * 4, stream);
  int eb = (NE + 255) / 256;
  count_kernel<<<eb, 256, 0, stream>>>(dst, counts, NE);
  scanA_kernel<<<SCAN_BLOCKS, 256, 0, stream>>>(counts, lscan, partials, NN);
  scanC_kernel<<<SCAN_BLOCKS, 256, 0, stream>>>(lscan, partials, SCAN_BLOCKS, row_ptr, fillp, NN);
  fill_kernel<<<eb, 256, 0, stream>>>(src, dst, fillp, es, NE);

  int gb = (NN + BM - 1) / BM;
  int nwb = (NN + 3) / 4;  // 4 waves (256 threads) per block, wave per node

  // conv0: 128 -> 128, LN1 + ReLU
  gemm_kernel<<<gb, 256, 0, stream>>>(feat, W0, ft, e_node, NN, 128);
  agg_kernel<128, true><<<nwb, 256, 0, stream>>>(ft, e_node, row_ptr, es, b0, ln1g, ln1b, h, NN);
  // conv1: 128 -> 128, LN2 + ReLU
  gemm_kernel<<<gb, 256, 0, stream>>>(h, W1, ft, e_node, NN, 128);
  agg_kernel<128, true><<<nwb, 256, 0, stream>>>(ft, e_node, row_ptr, es, b1, ln2g, ln2b, h, NN);
  // conv2: 128 -> 64, no LN
  gemm_kernel<<<gb, 256, 0, stream>>>(h, W2, ft, e_node, NN, 64);
  agg_kernel<64, false><<<nwb, 256, 0, stream>>>(ft, e_node, row_ptr, es, b2, nullptr, nullptr, out, NN);
}

// Round 3
// 453.081 us; speedup vs baseline: 1.5680x; 1.2685x over previous
//
#include <hip/hip_runtime.h>
#include <math.h>

#define NN 50000
#define NE 800000
#define KDIM 128

// ---------------- GEMM: Y[nrows x OUT] = X[nrows x 128] @ W[128 x OUT] ----------------
// fp32, LDS-tiled. BM=64, BN=128, KC=32, 256 threads, 4x8 micro-tile per thread.
// Epilogue also computes e_node[row] (fused cosine/log score).
constexpr int BM = 64, BN = 128, KC = 32;

__global__ __launch_bounds__(256) void gemm_kernel(
    const float* __restrict__ X, const float* __restrict__ W,
    float* __restrict__ Y, float* __restrict__ e_node, int nrows, int OUT) {
  __shared__ __align__(16) float XsT[KC][BM + 4];
  __shared__ __align__(16) float Ws[KC][BN + 4];
  const int tid = threadIdx.x;
  const int row0 = blockIdx.x * BM;
  const int c  = tid & 15;
  const int rg = tid >> 4;

  float acc[4][8];
#pragma unroll
  for (int i = 0; i < 4; i++)
#pragma unroll
    for (int j = 0; j < 8; j++) acc[i][j] = 0.f;

  const int lr  = tid >> 2;
  const int lq  = tid & 3;
  const int wk  = tid >> 3;
  const int ws0 = tid & 7;

  for (int k0 = 0; k0 < KDIM; k0 += KC) {
#pragma unroll
    for (int i = 0; i < 2; i++) {
      int slot = lq + i * 4;
      int kk = slot * 4;
      float4 v = make_float4(0.f, 0.f, 0.f, 0.f);
      int grow = row0 + lr;
      if (grow < nrows) v = *(const float4*)&X[(size_t)grow * KDIM + k0 + kk];
      XsT[kk + 0][lr] = v.x; XsT[kk + 1][lr] = v.y;
      XsT[kk + 2][lr] = v.z; XsT[kk + 3][lr] = v.w;
    }
#pragma unroll
    for (int i = 0; i < 4; i++) {
      int slot = ws0 + i * 8;
      int col4 = slot * 4;
      float4 v = make_float4(0.f, 0.f, 0.f, 0.f);
      if (col4 < OUT) v = *(const float4*)&W[(size_t)(k0 + wk) * OUT + col4];
      *(float4*)&Ws[wk][col4] = v;
    }
    __syncthreads();
#pragma unroll
    for (int k = 0; k < KC; ++k) {
      float4 a  = *(const float4*)&XsT[k][rg * 4];
      float4 p0 = *(const float4*)&Ws[k][c * 4];
      float4 p1 = *(const float4*)&Ws[k][c * 4 + 64];
      float av[4] = {a.x, a.y, a.z, a.w};
      float bv[8] = {p0.x, p0.y, p0.z, p0.w, p1.x, p1.y, p1.z, p1.w};
#pragma unroll
      for (int i = 0; i < 4; i++)
#pragma unroll
        for (int j = 0; j < 8; j++) acc[i][j] = fmaf(av[i], bv[j], acc[i][j]);
    }
    __syncthreads();
  }
#pragma unroll
  for (int i = 0; i < 4; i++) {
    int grow = row0 + rg * 4 + i;
    float s = 0.f;
#pragma unroll
    for (int j = 0; j < 8; j++) s = fmaf(acc[i][j], acc[i][j], s);
#pragma unroll
    for (int o = 8; o > 0; o >>= 1) s += __shfl_xor(s, o, 64);
    if (c == 0 && grow < nrows) {
      float nrm = fmaxf(sqrtf(s), 1e-8f);
      float cs = s / (nrm * nrm);
      e_node[grow] = logf(cs >= 0.1f ? cs : 1e-6f);
    }
    if (grow >= nrows) continue;
#pragma unroll
    for (int j = 0; j < 8; j++) {
      int col = (j < 4) ? (c * 4 + j) : (64 + c * 4 + (j - 4));
      if (col < OUT) Y[(size_t)grow * OUT + col] = acc[i][j];
    }
  }
}

// ---------------- segment softmax + weighted aggregation (+bias, +optional LN+ReLU) -----------
// Wave per dst node. Softmax weights precomputed lane-parallel per 64-edge chunk,
// broadcast via shfl into a multi-edge float4 gather loop:
//   F=128: 32 lanes/row -> 2 edges in flight;  F=64: 16 lanes/row -> 4 edges in flight.
template <int F, bool LN>
__global__ __launch_bounds__(256) void agg_kernel(
    const float* __restrict__ ft, const float* __restrict__ e_node,
    const int* __restrict__ row_ptr, const int* __restrict__ es,
    const float* __restrict__ bias, const float* __restrict__ g,
    const float* __restrict__ beta, float* __restrict__ out, int n) {
  int gw = (blockIdx.x * blockDim.x + threadIdx.x) >> 6;
  int lane = threadIdx.x & 63;
  if (gw >= n) return;
  int b = row_ptr[gw], e = row_ptr[gw + 1];
  // segment max (lane-parallel)
  float m = -INFINITY;
  for (int i = b + lane; i < e; i += 64) m = fmaxf(m, e_node[es[i]]);
#pragma unroll
  for (int o = 32; o > 0; o >>= 1) m = fmaxf(m, __shfl_xor(m, o, 64));
  // segment sum of exp (lane-parallel)
  float s = 0.f;
  for (int i = b + lane; i < e; i += 64) s += expf(e_node[es[i]] - m);
#pragma unroll
  for (int o = 32; o > 0; o >>= 1) s += __shfl_xor(s, o, 64);
  float inv = 1.0f / fmaxf(s, 1e-16f);

  constexpr int LPR = F / 4;          // lanes per row (float4 each): 32 or 16
  constexpr int EW  = 64 / LPR;       // edges in flight per wave: 2 or 4
  const int sub = lane / LPR;         // which concurrent edge stream
  const int ll  = lane % LPR;         // lane within row
  float4 acc = make_float4(0.f, 0.f, 0.f, 0.f);

  for (int cb = b; cb < e; cb += 64) {
    int rem = e - cb; if (rem > 64) rem = 64;
    int sn_l = 0; float a_l = 0.f;
    if (lane < rem) {
      sn_l = es[cb + lane];
      a_l = expf(e_node[sn_l] - m) * inv;
    }
    for (int j = 0; j < rem; j += EW) {
      int jj = j + sub;
      int sn = __shfl(sn_l, jj, 64);
      float a = __shfl(a_l, jj, 64);   // 0 for tail slots -> no-op accumulate
      float4 v = *(const float4*)&ft[(size_t)sn * F + ll * 4];
      acc.x = fmaf(v.x, a, acc.x);
      acc.y = fmaf(v.y, a, acc.y);
      acc.z = fmaf(v.z, a, acc.z);
      acc.w = fmaf(v.w, a, acc.w);
    }
  }
  // combine the EW edge streams (after this, every lane holds totals for cols ll*4..+3)
#pragma unroll
  for (int o = 32; o >= LPR; o >>= 1) {
    acc.x += __shfl_xor(acc.x, o, 64);
    acc.y += __shfl_xor(acc.y, o, 64);
    acc.z += __shfl_xor(acc.z, o, 64);
    acc.w += __shfl_xor(acc.w, o, 64);
  }
  float4 b4 = *(const float4*)&bias[ll * 4];
  acc.x += b4.x; acc.y += b4.y; acc.z += b4.z; acc.w += b4.w;
  if (LN) {
    float sum = acc.x + acc.y + acc.z + acc.w;
#pragma unroll
    for (int o = LPR / 2; o > 0; o >>= 1) sum += __shfl_xor(sum, o, 64);
    float mean = sum * (1.0f / 128.0f);
    float dx = acc.x - mean, dy = acc.y - mean, dz = acc.z - mean, dw = acc.w - mean;
    float v = dx * dx + dy * dy + dz * dz + dw * dw;
#pragma unroll
    for (int o = LPR / 2; o > 0; o >>= 1) v += __shfl_xor(v, o, 64);
    float r = rsqrtf(v * (1.0f / 128.0f) + 1e-5f);
    float4 g4 = *(const float4*)&g[ll * 4];
    float4 be4 = *(const float4*)&beta[ll * 4];
    float4 res;
    res.x = fmaxf(dx * r * g4.x + be4.x, 0.f);
    res.y = fmaxf(dy * r * g4.y + be4.y, 0.f);
    res.z = fmaxf(dz * r * g4.z + be4.z, 0.f);
    res.w = fmaxf(dw * r * g4.w + be4.w, 0.f);
    if (sub == 0) *(float4*)&out[(size_t)gw * F + ll * 4] = res;
  } else {
    if (sub == 0) *(float4*)&out[(size_t)gw * F + ll * 4] = acc;
  }
}

// ---------------- CSR build (by dst) ----------------
__global__ void count_kernel(const int* __restrict__ dst, int* __restrict__ counts, int E) {
  int e = blockIdx.x * blockDim.x + threadIdx.x;
  if (e < E) atomicAdd(&counts[dst[e]], 1);
}

__global__ __launch_bounds__(256) void scanA_kernel(
    const int* __restrict__ counts, int* __restrict__ lscan,
    int* __restrict__ partials, int n) {
  int tid = threadIdx.x;
  int base = blockIdx.x * 1024 + tid * 4;
  int4 v = make_int4(0, 0, 0, 0);
  if (base + 3 < n) v = *(const int4*)&counts[base];
  else {
    if (base + 0 < n) v.x = counts[base + 0];
    if (base + 1 < n) v.y = counts[base + 1];
    if (base + 2 < n) v.z = counts[base + 2];
  }
  int tsum = v.x + v.y + v.z + v.w;
  int lane = tid & 63, wid = tid >> 6;
  int x = tsum;
#pragma unroll
  for (int o = 1; o < 64; o <<= 1) {
    int y = __shfl_up(x, o, 64);
    if (lane >= o) x += y;
  }
  __shared__ int wsum[4];
  if (lane == 63) wsum[wid] = x;
  __syncthreads();
  int wpre = 0;
  for (int w = 0; w < wid; w++) wpre += wsum[w];
  int excl = wpre + x - tsum;
  int4 o4;
  o4.x = excl;
  o4.y = excl + v.x;
  o4.z = excl + v.x + v.y;
  o4.w = excl + v.x + v.y + v.z;
  if (base + 3 < n) *(int4*)&lscan[base] = o4;
  else {
    if (base + 0 < n) lscan[base + 0] = o4.x;
    if (base + 1 < n) lscan[base + 1] = o4.y;
    if (base + 2 < n) lscan[base + 2] = o4.z;
  }
  if (tid == 255) partials[blockIdx.x] = wpre + x;
}

__global__ __launch_bounds__(256) void scanC_kernel(
    const int* __restrict__ lscan, const int* __restrict__ partials, int nblocks,
    int* __restrict__ row_ptr, int* __restrict__ fillp, int n) {
  __shared__ int s_prefix;
  int tid = threadIdx.x;
  if (tid < 64) {
    int pv = (tid < nblocks && tid < (int)blockIdx.x) ? partials[tid] : 0;
#pragma unroll
    for (int o = 32; o > 0; o >>= 1) pv += __shfl_xor(pv, o, 64);
    if (tid == 0) s_prefix = pv;
  }
  __syncthreads();
  int prefix = s_prefix;
  int base = blockIdx.x * 1024 + tid * 4;
#pragma unroll
  for (int q = 0; q < 4; q++) {
    int idx = base + q;
    if (idx < n) {
      int v = lscan[idx] + prefix;
      row_ptr[idx] = v;
      fillp[idx] = v;
    }
  }
  if (blockIdx.x == 0 && tid == 0) row_ptr[n] = NE;
}

__global__ void fill_kernel(const int* __restrict__ src, const int* __restrict__ dst,
                            int* __restrict__ fillp, int* __restrict__ es, int E) {
  int e = blockIdx.x * blockDim.x + threadIdx.x;
  if (e < E) {
    int d = dst[e];
    int pos = atomicAdd(&fillp[d], 1);
    es[pos] = src[e];
  }
}

// ---------------- orchestration ----------------
extern "C" void kernel_launch(void* const* d_in, const int* in_sizes, int n_in,
                              void* d_out, int out_size, void* d_ws, size_t ws_size,
                              hipStream_t stream) {
  (void)in_sizes; (void)n_in; (void)out_size; (void)ws_size;
  const float* feat = (const float*)d_in[0];
  const int* src = (const int*)d_in[1];
  const int* dst = (const int*)d_in[2];
  const float* W0 = (const float*)d_in[3];
  const float* b0 = (const float*)d_in[4];
  const float* W1 = (const float*)d_in[5];
  const float* b1 = (const float*)d_in[6];
  const float* W2 = (const float*)d_in[7];
  const float* b2 = (const float*)d_in[8];
  const float* ln1g = (const float*)d_in[9];
  const float* ln1b = (const float*)d_in[10];
  const float* ln2g = (const float*)d_in[11];
  const float* ln2b = (const float*)d_in[12];
  float* out = (float*)d_out;

  char* p = (char*)d_ws;
  auto alloc = [&](size_t bytes) {
    char* r = p;
    p += (bytes + 255) & ~size_t(255);
    return r;
  };
  float* ft      = (float*)alloc((size_t)NN * 128 * 4);
  float* h       = (float*)alloc((size_t)NN * 128 * 4);
  float* e_node  = (float*)alloc((size_t)NN * 4);
  int* row_ptr   = (int*)alloc((size_t)(NN + 1) * 4);
  int* counts    = (int*)alloc((size_t)NN * 4);
  int* fillp     = (int*)alloc((size_t)NN * 4);
  int* es        = (int*)alloc((size_t)NE * 4);
  int* lscan     = (int*)alloc((size_t)NN * 4);
  int* partials  = (int*)alloc(64 * 4);

  const int SCAN_BLOCKS = (NN + 1023) / 1024;  // 49

  hipMemsetAsync(counts, 0, (size_t)NN * 4, stream);
  int eb = (NE + 255) / 256;
  count_kernel<<<eb, 256, 0, stream>>>(dst, counts, NE);
  scanA_kernel<<<SCAN_BLOCKS, 256, 0, stream>>>(counts, lscan, partials, NN);
  scanC_kernel<<<SCAN_BLOCKS, 256, 0, stream>>>(lscan, partials, SCAN_BLOCKS, row_ptr, fillp, NN);
  fill_kernel<<<eb, 256, 0, stream>>>(src, dst, fillp, es, NE);

  int gb = (NN + BM - 1) / BM;
  int nwb = (NN + 3) / 4;

  gemm_kernel<<<gb, 256, 0, stream>>>(feat, W0, ft, e_node, NN, 128);
  agg_kernel<128, true><<<nwb, 256, 0, stream>>>(ft, e_node, row_ptr, es, b0, ln1g, ln1b, h, NN);
  gemm_kernel<<<gb, 256, 0, stream>>>(h, W1, ft, e_node, NN, 128);
  agg_kernel<128, true><<<nwb, 256, 0, stream>>>(ft, e_node, row_ptr, es, b1, ln2g, ln2b, h, NN);
  gemm_kernel<<<gb, 256, 0, stream>>>(h, W2, ft, e_node, NN, 64);
  agg_kernel<64, false><<<nwb, 256, 0, stream>>>(ft, e_node, row_ptr, es, b2, nullptr, nullptr, out, NN);
}

// Round 5
// 395.481 us; speedup vs baseline: 1.7964x; 1.1456x over previous
//
#include <hip/hip_runtime.h>
#include <hip/hip_fp16.h>
#include <math.h>

#define NN 50000
#define NE 800000
#define KDIM 128

// ---------------- GEMM: Y[nrows x 128] @ W[128 x OUT] -> fp16 Y, fused e_node ----------------
constexpr int BM = 64, BN = 128, KC = 32;

__global__ __launch_bounds__(256) void gemm_kernel(
    const float* __restrict__ X, const float* __restrict__ W,
    __half* __restrict__ Y, float* __restrict__ e_node, int nrows, int OUT) {
  __shared__ __align__(16) float XsT[KC][BM + 4];
  __shared__ __align__(16) float Ws[KC][BN + 4];
  const int tid = threadIdx.x;
  const int row0 = blockIdx.x * BM;
  const int c  = tid & 15;
  const int rg = tid >> 4;

  float acc[4][8];
#pragma unroll
  for (int i = 0; i < 4; i++)
#pragma unroll
    for (int j = 0; j < 8; j++) acc[i][j] = 0.f;

  const int lr  = tid >> 2;
  const int lq  = tid & 3;
  const int wk  = tid >> 3;
  const int ws0 = tid & 7;

  for (int k0 = 0; k0 < KDIM; k0 += KC) {
#pragma unroll
    for (int i = 0; i < 2; i++) {
      int slot = lq + i * 4;
      int kk = slot * 4;
      float4 v = make_float4(0.f, 0.f, 0.f, 0.f);
      int grow = row0 + lr;
      if (grow < nrows) v = *(const float4*)&X[(size_t)grow * KDIM + k0 + kk];
      XsT[kk + 0][lr] = v.x; XsT[kk + 1][lr] = v.y;
      XsT[kk + 2][lr] = v.z; XsT[kk + 3][lr] = v.w;
    }
#pragma unroll
    for (int i = 0; i < 4; i++) {
      int slot = ws0 + i * 8;
      int col4 = slot * 4;
      float4 v = make_float4(0.f, 0.f, 0.f, 0.f);
      if (col4 < OUT) v = *(const float4*)&W[(size_t)(k0 + wk) * OUT + col4];
      *(float4*)&Ws[wk][col4] = v;
    }
    __syncthreads();
#pragma unroll
    for (int k = 0; k < KC; ++k) {
      float4 a  = *(const float4*)&XsT[k][rg * 4];
      float4 p0 = *(const float4*)&Ws[k][c * 4];
      float4 p1 = *(const float4*)&Ws[k][c * 4 + 64];
      float av[4] = {a.x, a.y, a.z, a.w};
      float bv[8] = {p0.x, p0.y, p0.z, p0.w, p1.x, p1.y, p1.z, p1.w};
#pragma unroll
      for (int i = 0; i < 4; i++)
#pragma unroll
        for (int j = 0; j < 8; j++) acc[i][j] = fmaf(av[i], bv[j], acc[i][j]);
    }
    __syncthreads();
  }
#pragma unroll
  for (int i = 0; i < 4; i++) {
    int grow = row0 + rg * 4 + i;
    float s = 0.f;
#pragma unroll
    for (int j = 0; j < 8; j++) s = fmaf(acc[i][j], acc[i][j], s);  // cols >= OUT are exact 0 (Ws zero-filled)
#pragma unroll
    for (int o = 8; o > 0; o >>= 1) s += __shfl_xor(s, o, 64);
    if (c == 0 && grow < nrows) {
      float nrm = fmaxf(sqrtf(s), 1e-8f);
      float cs = s / (nrm * nrm);
      e_node[grow] = logf(cs >= 0.1f ? cs : 1e-6f);
    }
    if (grow >= nrows) continue;
    __half2 h01 = __floats2half2_rn(acc[i][0], acc[i][1]);
    __half2 h23 = __floats2half2_rn(acc[i][2], acc[i][3]);
    *(__half2*)&Y[(size_t)grow * OUT + c * 4 + 0] = h01;
    *(__half2*)&Y[(size_t)grow * OUT + c * 4 + 2] = h23;
    if (64 + c * 4 < OUT) {
      __half2 h45 = __floats2half2_rn(acc[i][4], acc[i][5]);
      __half2 h67 = __floats2half2_rn(acc[i][6], acc[i][7]);
      *(__half2*)&Y[(size_t)grow * OUT + 64 + c * 4 + 0] = h45;
      *(__half2*)&Y[(size_t)grow * OUT + 64 + c * 4 + 2] = h67;
    }
  }
}

// ---------------- segment softmax + weighted aggregation (+bias, +optional LN+ReLU) -----------
// Wave per dst node, fp16 gather rows, R3-proven two-pass structure (no register fast path).
// 16B/lane: F=128 -> LPR=16, 4 edges in flight; F=64 -> LPR=8, 8 edges in flight.
template <int F, bool LN>
__global__ __launch_bounds__(256) void agg_kernel(
    const __half* __restrict__ ft, const float* __restrict__ e_node,
    const int* __restrict__ row_ptr, const int* __restrict__ es,
    const float* __restrict__ bias, const float* __restrict__ g,
    const float* __restrict__ beta, float* __restrict__ out, int n) {
  int gw = (blockIdx.x * blockDim.x + threadIdx.x) >> 6;
  int lane = threadIdx.x & 63;
  if (gw >= n) return;
  int b = row_ptr[gw], e = row_ptr[gw + 1];

  // segment max (lane-parallel)
  float m = -INFINITY;
  for (int i = b + lane; i < e; i += 64) m = fmaxf(m, e_node[es[i]]);
#pragma unroll
  for (int o = 32; o > 0; o >>= 1) m = fmaxf(m, __shfl_xor(m, o, 64));
  // segment sum of exp (lane-parallel)
  float s = 0.f;
  for (int i = b + lane; i < e; i += 64) s += expf(e_node[es[i]] - m);
#pragma unroll
  for (int o = 32; o > 0; o >>= 1) s += __shfl_xor(s, o, 64);
  float inv = 1.0f / fmaxf(s, 1e-16f);

  constexpr int LPR = F / 8;      // lanes per row (8 halves = 16B each)
  constexpr int EW  = 64 / LPR;   // edges in flight
  const int sub = lane / LPR;
  const int ll  = lane % LPR;
  float acc[8];
#pragma unroll
  for (int q = 0; q < 8; q++) acc[q] = 0.f;

  for (int cb = b; cb < e; cb += 64) {
    int rem = e - cb; if (rem > 64) rem = 64;
    int sn_l = 0; float a_l = 0.f;
    if (lane < rem) {
      sn_l = es[cb + lane];
      a_l = expf(e_node[sn_l] - m) * inv;
    }
    for (int j = 0; j < rem; j += EW) {
      int jj = j + sub;
      int sn = __shfl(sn_l, jj, 64);
      float a = __shfl(a_l, jj, 64);   // 0 for tail/invalid slots -> no-op accumulate
      union { float4 f4; __half2 h2[4]; } u;
      u.f4 = *(const float4*)&ft[(size_t)sn * F + ll * 8];
#pragma unroll
      for (int q = 0; q < 4; q++) {
        float2 f = __half22float2(u.h2[q]);
        acc[2 * q + 0] = fmaf(f.x, a, acc[2 * q + 0]);
        acc[2 * q + 1] = fmaf(f.y, a, acc[2 * q + 1]);
      }
    }
  }

  // combine the EW edge streams (sum over 'sub' lane bits)
#pragma unroll
  for (int o = 32; o >= LPR; o >>= 1)
#pragma unroll
    for (int q = 0; q < 8; q++) acc[q] += __shfl_xor(acc[q], o, 64);

  float4 b4a = *(const float4*)&bias[ll * 8 + 0];
  float4 b4b = *(const float4*)&bias[ll * 8 + 4];
  acc[0] += b4a.x; acc[1] += b4a.y; acc[2] += b4a.z; acc[3] += b4a.w;
  acc[4] += b4b.x; acc[5] += b4b.y; acc[6] += b4b.z; acc[7] += b4b.w;

  if (LN) {
    float sum = 0.f;
#pragma unroll
    for (int q = 0; q < 8; q++) sum += acc[q];
#pragma unroll
    for (int o = LPR / 2; o > 0; o >>= 1) sum += __shfl_xor(sum, o, 64);
    float mean = sum * (1.0f / 128.0f);
    float var = 0.f;
#pragma unroll
    for (int q = 0; q < 8; q++) { acc[q] -= mean; var = fmaf(acc[q], acc[q], var); }
#pragma unroll
    for (int o = LPR / 2; o > 0; o >>= 1) var += __shfl_xor(var, o, 64);
    float r = rsqrtf(var * (1.0f / 128.0f) + 1e-5f);
    float4 g4a = *(const float4*)&g[ll * 8 + 0];
    float4 g4b = *(const float4*)&g[ll * 8 + 4];
    float4 be4a = *(const float4*)&beta[ll * 8 + 0];
    float4 be4b = *(const float4*)&beta[ll * 8 + 4];
    float4 r0, r1;
    r0.x = fmaxf(acc[0] * r * g4a.x + be4a.x, 0.f);
    r0.y = fmaxf(acc[1] * r * g4a.y + be4a.y, 0.f);
    r0.z = fmaxf(acc[2] * r * g4a.z + be4a.z, 0.f);
    r0.w = fmaxf(acc[3] * r * g4a.w + be4a.w, 0.f);
    r1.x = fmaxf(acc[4] * r * g4b.x + be4b.x, 0.f);
    r1.y = fmaxf(acc[5] * r * g4b.y + be4b.y, 0.f);
    r1.z = fmaxf(acc[6] * r * g4b.z + be4b.z, 0.f);
    r1.w = fmaxf(acc[7] * r * g4b.w + be4b.w, 0.f);
    if (sub == 0) {
      *(float4*)&out[(size_t)gw * F + ll * 8 + 0] = r0;
      *(float4*)&out[(size_t)gw * F + ll * 8 + 4] = r1;
    }
  } else {
    if (sub == 0) {
      *(float4*)&out[(size_t)gw * F + ll * 8 + 0] = make_float4(acc[0], acc[1], acc[2], acc[3]);
      *(float4*)&out[(size_t)gw * F + ll * 8 + 4] = make_float4(acc[4], acc[5], acc[6], acc[7]);
    }
  }
}

// ---------------- CSR build (by dst) ----------------
__global__ void count_kernel(const int* __restrict__ dst, int* __restrict__ counts, int E) {
  int e = blockIdx.x * blockDim.x + threadIdx.x;
  if (e < E) atomicAdd(&counts[dst[e]], 1);
}

__global__ __launch_bounds__(256) void scanA_kernel(
    const int* __restrict__ counts, int* __restrict__ lscan,
    int* __restrict__ partials, int n) {
  int tid = threadIdx.x;
  int base = blockIdx.x * 1024 + tid * 4;
  int4 v = make_int4(0, 0, 0, 0);
  if (base + 3 < n) v = *(const int4*)&counts[base];
  else {
    if (base + 0 < n) v.x = counts[base + 0];
    if (base + 1 < n) v.y = counts[base + 1];
    if (base + 2 < n) v.z = counts[base + 2];
  }
  int tsum = v.x + v.y + v.z + v.w;
  int lane = tid & 63, wid = tid >> 6;
  int x = tsum;
#pragma unroll
  for (int o = 1; o < 64; o <<= 1) {
    int y = __shfl_up(x, o, 64);
    if (lane >= o) x += y;
  }
  __shared__ int wsum[4];
  if (lane == 63) wsum[wid] = x;
  __syncthreads();
  int wpre = 0;
  for (int w = 0; w < wid; w++) wpre += wsum[w];
  int excl = wpre + x - tsum;
  int4 o4;
  o4.x = excl;
  o4.y = excl + v.x;
  o4.z = excl + v.x + v.y;
  o4.w = excl + v.x + v.y + v.z;
  if (base + 3 < n) *(int4*)&lscan[base] = o4;
  else {
    if (base + 0 < n) lscan[base + 0] = o4.x;
    if (base + 1 < n) lscan[base + 1] = o4.y;
    if (base + 2 < n) lscan[base + 2] = o4.z;
  }
  if (tid == 255) partials[blockIdx.x] = wpre + x;
}

__global__ __launch_bounds__(256) void scanC_kernel(
    const int* __restrict__ lscan, const int* __restrict__ partials, int nblocks,
    int* __restrict__ row_ptr, int* __restrict__ fillp, int n) {
  __shared__ int s_prefix;
  int tid = threadIdx.x;
  if (tid < 64) {
    int pv = (tid < nblocks && tid < (int)blockIdx.x) ? partials[tid] : 0;
#pragma unroll
    for (int o = 32; o > 0; o >>= 1) pv += __shfl_xor(pv, o, 64);
    if (tid == 0) s_prefix = pv;
  }
  __syncthreads();
  int prefix = s_prefix;
  int base = blockIdx.x * 1024 + tid * 4;
#pragma unroll
  for (int q = 0; q < 4; q++) {
    int idx = base + q;
    if (idx < n) {
      int v = lscan[idx] + prefix;
      row_ptr[idx] = v;
      fillp[idx] = v;
    }
  }
  if (blockIdx.x == 0 && tid == 0) row_ptr[n] = NE;
}

__global__ void fill_kernel(const int* __restrict__ src, const int* __restrict__ dst,
                            int* __restrict__ fillp, int* __restrict__ es, int E) {
  int e = blockIdx.x * blockDim.x + threadIdx.x;
  if (e < E) {
    int d = dst[e];
    int pos = atomicAdd(&fillp[d], 1);
    es[pos] = src[e];
  }
}

// ---------------- orchestration ----------------
extern "C" void kernel_launch(void* const* d_in, const int* in_sizes, int n_in,
                              void* d_out, int out_size, void* d_ws, size_t ws_size,
                              hipStream_t stream) {
  (void)in_sizes; (void)n_in; (void)out_size; (void)ws_size;
  const float* feat = (const float*)d_in[0];
  const int* src = (const int*)d_in[1];
  const int* dst = (const int*)d_in[2];
  const float* W0 = (const float*)d_in[3];
  const float* b0 = (const float*)d_in[4];
  const float* W1 = (const float*)d_in[5];
  const float* b1 = (const float*)d_in[6];
  const float* W2 = (const float*)d_in[7];
  const float* b2 = (const float*)d_in[8];
  const float* ln1g = (const float*)d_in[9];
  const float* ln1b = (const float*)d_in[10];
  const float* ln2g = (const float*)d_in[11];
  const float* ln2b = (const float*)d_in[12];
  float* out = (float*)d_out;

  char* p = (char*)d_ws;
  auto alloc = [&](size_t bytes) {
    char* r = p;
    p += (bytes + 255) & ~size_t(255);
    return r;
  };
  __half* fth    = (__half*)alloc((size_t)NN * 128 * 2);
  float* h       = (float*)alloc((size_t)NN * 128 * 4);
  float* e_node  = (float*)alloc((size_t)NN * 4);
  int* row_ptr   = (int*)alloc((size_t)(NN + 1) * 4);
  int* counts    = (int*)alloc((size_t)NN * 4);
  int* fillp     = (int*)alloc((size_t)NN * 4);
  int* es        = (int*)alloc((size_t)NE * 4);
  int* lscan     = (int*)alloc((size_t)NN * 4);
  int* partials  = (int*)alloc(64 * 4);

  const int SCAN_BLOCKS = (NN + 1023) / 1024;  // 49

  hipMemsetAsync(counts, 0, (size_t)NN * 4, stream);
  int eb = (NE + 255) / 256;
  count_kernel<<<eb, 256, 0, stream>>>(dst, counts, NE);
  scanA_kernel<<<SCAN_BLOCKS, 256, 0, stream>>>(counts, lscan, partials, NN);
  scanC_kernel<<<SCAN_BLOCKS, 256, 0, stream>>>(lscan, partials, SCAN_BLOCKS, row_ptr, fillp, NN);
  fill_kernel<<<eb, 256, 0, stream>>>(src, dst, fillp, es, NE);

  int gb = (NN + BM - 1) / BM;
  int nwb = (NN + 3) / 4;

  gemm_kernel<<<gb, 256, 0, stream>>>(feat, W0, fth, e_node, NN, 128);
  agg_kernel<128, true><<<nwb, 256, 0, stream>>>(fth, e_node, row_ptr, es, b0, ln1g, ln1b, h, NN);
  gemm_kernel<<<gb, 256, 0, stream>>>(h, W1, fth, e_node, NN, 128);
  agg_kernel<128, true><<<nwb, 256, 0, stream>>>(fth, e_node, row_ptr, es, b1, ln2g, ln2b, h, NN);
  gemm_kernel<<<gb, 256, 0, stream>>>(h, W2, fth, e_node, NN, 64);
  agg_kernel<64, false><<<nwb, 256, 0, stream>>>(fth, e_node, row_ptr, es, b2, nullptr, nullptr, out, NN);
}

// Round 6
// 359.742 us; speedup vs baseline: 1.9749x; 1.0993x over previous
//
#include <hip/hip_runtime.h>
#include <hip/hip_fp16.h>
#include <math.h>

#define NN 50000
#define NE 800000
#define KDIM 128

// ---------------- GEMM: Y[nrows x 128] @ W[128 x OUT] -> fp16 Y ----------------
// fp32 compute, LDS-tiled. BM=64, BN=128, KC=32, 256 threads, 4x8 micro-tile.
constexpr int BM = 64, BN = 128, KC = 32;

__global__ __launch_bounds__(256) void gemm_kernel(
    const float* __restrict__ X, const float* __restrict__ W,
    __half* __restrict__ Y, int nrows, int OUT) {
  __shared__ __align__(16) float XsT[KC][BM + 4];
  __shared__ __align__(16) float Ws[KC][BN + 4];
  const int tid = threadIdx.x;
  const int row0 = blockIdx.x * BM;
  const int c  = tid & 15;
  const int rg = tid >> 4;

  float acc[4][8];
#pragma unroll
  for (int i = 0; i < 4; i++)
#pragma unroll
    for (int j = 0; j < 8; j++) acc[i][j] = 0.f;

  const int lr  = tid >> 2;
  const int lq  = tid & 3;
  const int wk  = tid >> 3;
  const int ws0 = tid & 7;

  for (int k0 = 0; k0 < KDIM; k0 += KC) {
#pragma unroll
    for (int i = 0; i < 2; i++) {
      int slot = lq + i * 4;
      int kk = slot * 4;
      float4 v = make_float4(0.f, 0.f, 0.f, 0.f);
      int grow = row0 + lr;
      if (grow < nrows) v = *(const float4*)&X[(size_t)grow * KDIM + k0 + kk];
      XsT[kk + 0][lr] = v.x; XsT[kk + 1][lr] = v.y;
      XsT[kk + 2][lr] = v.z; XsT[kk + 3][lr] = v.w;
    }
#pragma unroll
    for (int i = 0; i < 4; i++) {
      int slot = ws0 + i * 8;
      int col4 = slot * 4;
      float4 v = make_float4(0.f, 0.f, 0.f, 0.f);
      if (col4 < OUT) v = *(const float4*)&W[(size_t)(k0 + wk) * OUT + col4];
      *(float4*)&Ws[wk][col4] = v;
    }
    __syncthreads();
#pragma unroll
    for (int k = 0; k < KC; ++k) {
      float4 a  = *(const float4*)&XsT[k][rg * 4];
      float4 p0 = *(const float4*)&Ws[k][c * 4];
      float4 p1 = *(const float4*)&Ws[k][c * 4 + 64];
      float av[4] = {a.x, a.y, a.z, a.w};
      float bv[8] = {p0.x, p0.y, p0.z, p0.w, p1.x, p1.y, p1.z, p1.w};
#pragma unroll
      for (int i = 0; i < 4; i++)
#pragma unroll
        for (int j = 0; j < 8; j++) acc[i][j] = fmaf(av[i], bv[j], acc[i][j]);
    }
    __syncthreads();
  }
#pragma unroll
  for (int i = 0; i < 4; i++) {
    int grow = row0 + rg * 4 + i;
    if (grow >= nrows) continue;
    __half2 h01 = __floats2half2_rn(acc[i][0], acc[i][1]);
    __half2 h23 = __floats2half2_rn(acc[i][2], acc[i][3]);
    *(__half2*)&Y[(size_t)grow * OUT + c * 4 + 0] = h01;
    *(__half2*)&Y[(size_t)grow * OUT + c * 4 + 2] = h23;
    if (64 + c * 4 < OUT) {
      __half2 h45 = __floats2half2_rn(acc[i][4], acc[i][5]);
      __half2 h67 = __floats2half2_rn(acc[i][6], acc[i][7]);
      *(__half2*)&Y[(size_t)grow * OUT + 64 + c * 4 + 0] = h45;
      *(__half2*)&Y[(size_t)grow * OUT + 64 + c * 4 + 2] = h67;
    }
  }
}

// ---------------- mean aggregation (+bias, +optional LN+ReLU) -----------
// Softmax weights are uniform to ~1e-7 (cos==1 +-1ulp for nonzero rows; e_node = log(1) ~ 0;
// segment softmax of equal scores = 1/deg), so aggregate = mean of gathered rows.
// Wave per dst node, fp16 rows, 16B/lane: F=128 -> LPR=16, 4 edges in flight; F=64 -> LPR=8, 8.
template <int F, bool LN>
__global__ __launch_bounds__(256) void agg_kernel(
    const __half* __restrict__ ft,
    const int* __restrict__ row_ptr, const int* __restrict__ es,
    const float* __restrict__ bias, const float* __restrict__ g,
    const float* __restrict__ beta, float* __restrict__ out, int n) {
  int gw = (blockIdx.x * blockDim.x + threadIdx.x) >> 6;
  int lane = threadIdx.x & 63;
  if (gw >= n) return;
  int b = row_ptr[gw], e = row_ptr[gw + 1];
  int deg = e - b;

  constexpr int LPR = F / 8;      // lanes per row (8 halves = 16B each)
  constexpr int EW  = 64 / LPR;   // edges in flight
  const int sub = lane / LPR;
  const int ll  = lane % LPR;
  float acc[8];
#pragma unroll
  for (int q = 0; q < 8; q++) acc[q] = 0.f;

  for (int cb = b; cb < e; cb += 64) {
    int rem = e - cb; if (rem > 64) rem = 64;
    int sn_l = 0;
    if (lane < rem) sn_l = es[cb + lane];
    for (int j = 0; j < rem; j += EW) {
      int jj = j + sub;
      int sn = __shfl(sn_l, jj, 64);
      if (jj < rem) {
        union { float4 f4; __half2 h2[4]; } u;
        u.f4 = *(const float4*)&ft[(size_t)sn * F + ll * 8];
#pragma unroll
        for (int q = 0; q < 4; q++) {
          float2 f = __half22float2(u.h2[q]);
          acc[2 * q + 0] += f.x;
          acc[2 * q + 1] += f.y;
        }
      }
    }
  }

  // combine the EW edge streams (sum over 'sub' lane bits)
#pragma unroll
  for (int o = 32; o >= LPR; o >>= 1)
#pragma unroll
    for (int q = 0; q < 8; q++) acc[q] += __shfl_xor(acc[q], o, 64);

  float sc = (deg > 0) ? (1.0f / (float)deg) : 0.f;
  float4 b4a = *(const float4*)&bias[ll * 8 + 0];
  float4 b4b = *(const float4*)&bias[ll * 8 + 4];
  acc[0] = fmaf(acc[0], sc, b4a.x); acc[1] = fmaf(acc[1], sc, b4a.y);
  acc[2] = fmaf(acc[2], sc, b4a.z); acc[3] = fmaf(acc[3], sc, b4a.w);
  acc[4] = fmaf(acc[4], sc, b4b.x); acc[5] = fmaf(acc[5], sc, b4b.y);
  acc[6] = fmaf(acc[6], sc, b4b.z); acc[7] = fmaf(acc[7], sc, b4b.w);

  if (LN) {
    float sum = 0.f;
#pragma unroll
    for (int q = 0; q < 8; q++) sum += acc[q];
#pragma unroll
    for (int o = LPR / 2; o > 0; o >>= 1) sum += __shfl_xor(sum, o, 64);
    float mean = sum * (1.0f / 128.0f);
    float var = 0.f;
#pragma unroll
    for (int q = 0; q < 8; q++) { acc[q] -= mean; var = fmaf(acc[q], acc[q], var); }
#pragma unroll
    for (int o = LPR / 2; o > 0; o >>= 1) var += __shfl_xor(var, o, 64);
    float r = rsqrtf(var * (1.0f / 128.0f) + 1e-5f);
    float4 g4a = *(const float4*)&g[ll * 8 + 0];
    float4 g4b = *(const float4*)&g[ll * 8 + 4];
    float4 be4a = *(const float4*)&beta[ll * 8 + 0];
    float4 be4b = *(const float4*)&beta[ll * 8 + 4];
    float4 r0, r1;
    r0.x = fmaxf(acc[0] * r * g4a.x + be4a.x, 0.f);
    r0.y = fmaxf(acc[1] * r * g4a.y + be4a.y, 0.f);
    r0.z = fmaxf(acc[2] * r * g4a.z + be4a.z, 0.f);
    r0.w = fmaxf(acc[3] * r * g4a.w + be4a.w, 0.f);
    r1.x = fmaxf(acc[4] * r * g4b.x + be4b.x, 0.f);
    r1.y = fmaxf(acc[5] * r * g4b.y + be4b.y, 0.f);
    r1.z = fmaxf(acc[6] * r * g4b.z + be4b.z, 0.f);
    r1.w = fmaxf(acc[7] * r * g4b.w + be4b.w, 0.f);
    if (sub == 0) {
      *(float4*)&out[(size_t)gw * F + ll * 8 + 0] = r0;
      *(float4*)&out[(size_t)gw * F + ll * 8 + 4] = r1;
    }
  } else {
    if (sub == 0) {
      *(float4*)&out[(size_t)gw * F + ll * 8 + 0] = make_float4(acc[0], acc[1], acc[2], acc[3]);
      *(float4*)&out[(size_t)gw * F + ll * 8 + 4] = make_float4(acc[4], acc[5], acc[6], acc[7]);
    }
  }
}

// ---------------- CSR build (by dst) ----------------
__global__ void count_kernel(const int* __restrict__ dst, int* __restrict__ counts, int E) {
  int e = blockIdx.x * blockDim.x + threadIdx.x;
  if (e < E) atomicAdd(&counts[dst[e]], 1);
}

__global__ __launch_bounds__(256) void scanA_kernel(
    const int* __restrict__ counts, int* __restrict__ lscan,
    int* __restrict__ partials, int n) {
  int tid = threadIdx.x;
  int base = blockIdx.x * 1024 + tid * 4;
  int4 v = make_int4(0, 0, 0, 0);
  if (base + 3 < n) v = *(const int4*)&counts[base];
  else {
    if (base + 0 < n) v.x = counts[base + 0];
    if (base + 1 < n) v.y = counts[base + 1];
    if (base + 2 < n) v.z = counts[base + 2];
  }
  int tsum = v.x + v.y + v.z + v.w;
  int lane = tid & 63, wid = tid >> 6;
  int x = tsum;
#pragma unroll
  for (int o = 1; o < 64; o <<= 1) {
    int y = __shfl_up(x, o, 64);
    if (lane >= o) x += y;
  }
  __shared__ int wsum[4];
  if (lane == 63) wsum[wid] = x;
  __syncthreads();
  int wpre = 0;
  for (int w = 0; w < wid; w++) wpre += wsum[w];
  int excl = wpre + x - tsum;
  int4 o4;
  o4.x = excl;
  o4.y = excl + v.x;
  o4.z = excl + v.x + v.y;
  o4.w = excl + v.x + v.y + v.z;
  if (base + 3 < n) *(int4*)&lscan[base] = o4;
  else {
    if (base + 0 < n) lscan[base + 0] = o4.x;
    if (base + 1 < n) lscan[base + 1] = o4.y;
    if (base + 2 < n) lscan[base + 2] = o4.z;
  }
  if (tid == 255) partials[blockIdx.x] = wpre + x;
}

__global__ __launch_bounds__(256) void scanC_kernel(
    const int* __restrict__ lscan, const int* __restrict__ partials, int nblocks,
    int* __restrict__ row_ptr, int* __restrict__ fillp, int n) {
  __shared__ int s_prefix;
  int tid = threadIdx.x;
  if (tid < 64) {
    int pv = (tid < nblocks && tid < (int)blockIdx.x) ? partials[tid] : 0;
#pragma unroll
    for (int o = 32; o > 0; o >>= 1) pv += __shfl_xor(pv, o, 64);
    if (tid == 0) s_prefix = pv;
  }
  __syncthreads();
  int prefix = s_prefix;
  int base = blockIdx.x * 1024 + tid * 4;
#pragma unroll
  for (int q = 0; q < 4; q++) {
    int idx = base + q;
    if (idx < n) {
      int v = lscan[idx] + prefix;
      row_ptr[idx] = v;
      fillp[idx] = v;
    }
  }
  if (blockIdx.x == 0 && tid == 0) row_ptr[n] = NE;
}

__global__ void fill_kernel(const int* __restrict__ src, const int* __restrict__ dst,
                            int* __restrict__ fillp, int* __restrict__ es, int E) {
  int e = blockIdx.x * blockDim.x + threadIdx.x;
  if (e < E) {
    int d = dst[e];
    int pos = atomicAdd(&fillp[d], 1);
    es[pos] = src[e];
  }
}

// ---------------- orchestration ----------------
extern "C" void kernel_launch(void* const* d_in, const int* in_sizes, int n_in,
                              void* d_out, int out_size, void* d_ws, size_t ws_size,
                              hipStream_t stream) {
  (void)in_sizes; (void)n_in; (void)out_size; (void)ws_size;
  const float* feat = (const float*)d_in[0];
  const int* src = (const int*)d_in[1];
  const int* dst = (const int*)d_in[2];
  const float* W0 = (const float*)d_in[3];
  const float* b0 = (const float*)d_in[4];
  const float* W1 = (const float*)d_in[5];
  const float* b1 = (const float*)d_in[6];
  const float* W2 = (const float*)d_in[7];
  const float* b2 = (const float*)d_in[8];
  const float* ln1g = (const float*)d_in[9];
  const float* ln1b = (const float*)d_in[10];
  const float* ln2g = (const float*)d_in[11];
  const float* ln2b = (const float*)d_in[12];
  float* out = (float*)d_out;

  char* p = (char*)d_ws;
  auto alloc = [&](size_t bytes) {
    char* r = p;
    p += (bytes + 255) & ~size_t(255);
    return r;
  };
  __half* fth    = (__half*)alloc((size_t)NN * 128 * 2);
  float* h       = (float*)alloc((size_t)NN * 128 * 4);
  int* row_ptr   = (int*)alloc((size_t)(NN + 1) * 4);
  int* counts    = (int*)alloc((size_t)NN * 4);
  int* fillp     = (int*)alloc((size_t)NN * 4);
  int* es        = (int*)alloc((size_t)NE * 4);
  int* lscan     = (int*)alloc((size_t)NN * 4);
  int* partials  = (int*)alloc(64 * 4);

  const int SCAN_BLOCKS = (NN + 1023) / 1024;  // 49

  hipMemsetAsync(counts, 0, (size_t)NN * 4, stream);
  int eb = (NE + 255) / 256;
  count_kernel<<<eb, 256, 0, stream>>>(dst, counts, NE);
  scanA_kernel<<<SCAN_BLOCKS, 256, 0, stream>>>(counts, lscan, partials, NN);
  scanC_kernel<<<SCAN_BLOCKS, 256, 0, stream>>>(lscan, partials, SCAN_BLOCKS, row_ptr, fillp, NN);
  fill_kernel<<<eb, 256, 0, stream>>>(src, dst, fillp, es, NE);

  int gb = (NN + BM - 1) / BM;
  int nwb = (NN + 3) / 4;

  gemm_kernel<<<gb, 256, 0, stream>>>(feat, W0, fth, NN, 128);
  agg_kernel<128, true><<<nwb, 256, 0, stream>>>(fth, row_ptr, es, b0, ln1g, ln1b, h, NN);
  gemm_kernel<<<gb, 256, 0, stream>>>(h, W1, fth, NN, 128);
  agg_kernel<128, true><<<nwb, 256, 0, stream>>>(fth, row_ptr, es, b1, ln2g, ln2b, h, NN);
  gemm_kernel<<<gb, 256, 0, stream>>>(h, W2, fth, NN, 64);
  agg_kernel<64, false><<<nwb, 256, 0, stream>>>(fth, row_ptr, es, b2, nullptr, nullptr, out, NN);
}